// Round 3
// baseline (1048.416 us; speedup 1.0000x reference)
//
#include <hip/hip_runtime.h>
#include <hip/hip_bf16.h>

// Nystromformer layer, MI355X. fp32 I/O (per reference dtypes), f16 MFMA
// internals, fp32 Newton-Schulz pinv chain.
// R3 fix: inputs/outputs are float32 (reference setup_inputs is jnp.float32);
// rounds 1-2 mis-cast them as bf16 => NaN bit patterns directly in x/w.
// Kept R2 fix: gemm256 LDS pad = 72 floats (288B row stride, 16B-aligned).

typedef _Float16 f16;
typedef f16 f16x2 __attribute__((ext_vector_type(2)));
typedef f16 f16x4 __attribute__((ext_vector_type(4)));
typedef f16 f16x8 __attribute__((ext_vector_type(8)));
typedef float f32x4 __attribute__((ext_vector_type(4)));

__device__ __forceinline__ float waveMax(float v){
  #pragma unroll
  for(int i=32;i>0;i>>=1) v = fmaxf(v, __shfl_xor(v, i));
  return v;
}
__device__ __forceinline__ float waveSum(float v){
  #pragma unroll
  for(int i=32;i>0;i>>=1) v += __shfl_xor(v, i);
  return v;
}
__device__ __forceinline__ float blockMaxF(float v, float* sm){
  v = waveMax(v);
  if((threadIdx.x&63)==0) sm[threadIdx.x>>6] = v;
  __syncthreads();
  v = fmaxf(fmaxf(sm[0],sm[1]), fmaxf(sm[2],sm[3]));
  __syncthreads();
  return v;
}
__device__ __forceinline__ float blockSumF(float v, float* sm){
  v = waveSum(v);
  if((threadIdx.x&63)==0) sm[threadIdx.x>>6] = v;
  __syncthreads();
  v = sm[0]+sm[1]+sm[2]+sm[3];
  __syncthreads();
  return v;
}

__device__ __forceinline__ void st_out(float* p, float v){ *p = v; }
__device__ __forceinline__ void st_out(f16* p, float v){ *p = (f16)v; }

__device__ __forceinline__ void async_cp16(const f16* g, const f16* l){
  __builtin_amdgcn_global_load_lds((const __attribute__((address_space(1))) void*)g,
                                   (__attribute__((address_space(3))) void*)l, 16, 0, 0);
}

// ---------------- LayerNorm: x fp32 [16384][512] -> xn f16 -------------------
__global__ __launch_bounds__(256) void k_ln(const float* __restrict__ x, const float* __restrict__ g,
                                            const float* __restrict__ be, f16* __restrict__ xn){
  __shared__ float sm[8];
  long row = blockIdx.x; int t = threadIdx.x;
  const float* xr = x + row*512;
  float v0 = xr[t], v1 = xr[t+256];
  float s = waveSum(v0+v1), ss = waveSum(v0*v0+v1*v1);
  if((t&63)==0){ sm[t>>6] = s; sm[(t>>6)+4] = ss; }
  __syncthreads();
  s = sm[0]+sm[1]+sm[2]+sm[3]; ss = sm[4]+sm[5]+sm[6]+sm[7];
  float mu = s*(1.f/512.f);
  float var = ss*(1.f/512.f) - mu*mu;
  float rstd = rsqrtf(var + 1e-5f);
  xn[row*512+t]     = (f16)((v0-mu)*rstd*g[t]     + be[t]);
  xn[row*512+t+256] = (f16)((v1-mu)*rstd*g[t+256] + be[t+256]);
}

// ------------- transpose w_qkv fp32 [512][192] -> wqkT f16 [256(pad)][512] ---
__global__ __launch_bounds__(256) void k_trw(const float* __restrict__ w, f16* __restrict__ wT){
  int i = blockIdx.x*256 + threadIdx.x;   // 131072
  int n = i>>9, k = i&511;
  wT[i] = (n<192) ? (f16)w[k*192+n] : (f16)0.0f;
}

// ---------------- shared MFMA GEMM: C[M][N] = A[M][K] * Bt[N][K]^T -----------
// 128x128 tile, BK=64, 4 waves (2x2 of 64x64), 16x16x32 f16 MFMA.
template<typename OutT>
__global__ __launch_bounds__(256) void gemm_bt(
    const f16* __restrict__ A, const f16* __restrict__ Bt, OutT* __restrict__ C,
    int M, int N, int K, long sA, long sB, long sC)
{
  __shared__ f16 As[8192];
  __shared__ f16 Bs[8192];
  int b = blockIdx.z;
  A  += (long)b * sA;  Bt += (long)b * sB;  C += (long)b * sC;
  int m0 = blockIdx.x*128, n0 = blockIdx.y*128;
  int t = threadIdx.x;
  int w = t>>6, lane = t&63;
  int quad = lane>>4, l16 = lane&15;
  int wr = w>>1, wc = w&1;
  f32x4 acc[4][4] = {};
  for(int kt=0; kt<(K>>6); ++kt){
    #pragma unroll
    for(int i=0;i<4;++i){
      int G = (w<<8)+(i<<6)+lane;
      int row = G>>3, gs = G&7;
      int g = gs ^ (row&7);                       // XOR-swizzled granule
      int koff = (kt<<6)+(g<<3);
      const f16* ldst = As + (((w<<8)+(i<<6))<<3);  // wave-uniform base
      async_cp16(A + (long)(m0+row)*K + koff, ldst);
      const f16* ldst2 = Bs + (((w<<8)+(i<<6))<<3);
      async_cp16(Bt + (long)(n0+row)*K + koff, ldst2);
    }
    __syncthreads();
    #pragma unroll
    for(int kk=0; kk<2; ++kk){
      f16x8 af[4], bfr[4];
      int gb = (kk<<2) + quad;
      #pragma unroll
      for(int mi=0;mi<4;++mi){
        int row = (wr<<6)+(mi<<4)+l16;
        af[mi] = *(const f16x8*)(As + ((row<<6) + ((gb ^ (row&7))<<3)));
      }
      #pragma unroll
      for(int ni=0;ni<4;++ni){
        int row = (wc<<6)+(ni<<4)+l16;
        bfr[ni] = *(const f16x8*)(Bs + ((row<<6) + ((gb ^ (row&7))<<3)));
      }
      #pragma unroll
      for(int mi=0;mi<4;++mi){
        #pragma unroll
        for(int ni=0;ni<4;++ni)
          acc[mi][ni] = __builtin_amdgcn_mfma_f32_16x16x32_f16(af[mi], bfr[ni], acc[mi][ni], 0,0,0);
      }
    }
    __syncthreads();
  }
  #pragma unroll
  for(int mi=0;mi<4;++mi){
    int rowb = m0 + (wr<<6) + (mi<<4) + (quad<<2);
    #pragma unroll
    for(int ni=0;ni<4;++ni){
      int col = n0 + (wc<<6) + (ni<<4) + l16;
      if(col < N){
        #pragma unroll
        for(int r=0;r<4;++r) st_out(C + (long)(rowb+r)*N + col, acc[mi][ni][r]);
      }
    }
  }
}

// ---------------- split qkv fp32 [16384][192] -> qf16(*0.125), kf16, vf32 ----
__global__ __launch_bounds__(256) void k_split(const float* __restrict__ qkv,
    f16* __restrict__ qf, f16* __restrict__ kf, float* __restrict__ vf){
  int t = threadIdx.x;
  long row = (long)blockIdx.x*4 + (t>>6); int d = t&63;
  const float* p = qkv + row*192;
  qf[row*64+d] = (f16)(p[d]*0.125f);
  kf[row*64+d] = (f16)(p[d+64]);
  vf[row*64+d] = p[d+128];
}

// ---------------- v transpose: vf32 [b][4096][64] -> vT f16 [b][128pad][4096]
__global__ __launch_bounds__(256) void k_vT(const float* __restrict__ vf, f16* __restrict__ vT){
  __shared__ float tile[64][65];
  int b = blockIdx.y, n0 = blockIdx.x*64;
  int t = threadIdx.x; int c = t&63, r4 = t>>6;
  #pragma unroll
  for(int i=0;i<16;++i){ int r = i*4+r4; tile[r][c] = vf[((long)(b*4096 + n0 + r))*64 + c]; }
  __syncthreads();
  #pragma unroll
  for(int i=0;i<16;++i){ int d = i*4+r4;
    vT[((long)(b*128 + d))*4096 + n0 + c] = (f16)tile[c][d]; }
}

// ---------------- landmarks: mean over 16 consecutive rows -------------------
__global__ __launch_bounds__(256) void k_land(const f16* __restrict__ qf, const f16* __restrict__ kf,
                                              f16* __restrict__ ql, f16* __restrict__ kl){
  int t = threadIdx.x;
  int bm = blockIdx.x*4 + (t>>6); int d = t&63;   // bm in [0,1024)
  const f16* pq = qf + (long)bm*1024 + d;
  const f16* pk = kf + (long)bm*1024 + d;
  float sq=0.f, sk=0.f;
  #pragma unroll
  for(int i=0;i<16;++i){ sq += (float)pq[i*64]; sk += (float)pk[i*64]; }
  ql[bm*64+d] = (f16)(sq*0.0625f);
  kl[bm*64+d] = (f16)(sk*0.0625f);
}

// ---------------- softmax over 256 cols, wave per row, out f16 ---------------
__global__ __launch_bounds__(256) void k_softmax1(const float* __restrict__ s, f16* __restrict__ a){
  int t = threadIdx.x; int w = t>>6, lane = t&63;
  long row = (long)blockIdx.x*4 + w;
  float4 v = *(const float4*)(s + row*256 + lane*4);
  float m = waveMax(fmaxf(fmaxf(v.x,v.y),fmaxf(v.z,v.w)));
  float e0 = __expf(v.x-m), e1 = __expf(v.y-m), e2 = __expf(v.z-m), e3 = __expf(v.w-m);
  float inv = 1.f/waveSum(e0+e1+e2+e3);
  f16x4 o = {(f16)(e0*inv),(f16)(e1*inv),(f16)(e2*inv),(f16)(e3*inv)};
  *(f16x4*)(a + row*256 + lane*4) = o;
}

// ------- softmax2: a2 fp32 + column-sum atomics (rs) + rowsum max (csmax) ----
__global__ __launch_bounds__(256) void k_softmax2(const float* __restrict__ s, float* __restrict__ a2,
                                                  float* __restrict__ rs, unsigned* __restrict__ csmax){
  __shared__ float sm[4];
  int row = blockIdx.x; int t = threadIdx.x; int b = row>>8;
  float v = s[row*256+t];
  float m = blockMaxF(v, sm);
  float e = __expf(v-m);
  float sum = blockSumF(e, sm);
  float p = e/sum;
  a2[(long)row*256+t] = p;
  atomicAdd(&rs[b*256+t], p);
  float rowsum = blockSumF(p, sm);
  if(t==0) atomicMax(csmax, __float_as_uint(rowsum));
}

// ---------------- softmax over 4096 cols, block per row, out f16 -------------
__global__ __launch_bounds__(256) void k_softmax3(const float* __restrict__ s, f16* __restrict__ a){
  __shared__ float sm[4];
  long row = blockIdx.x; int t = threadIdx.x;
  const float* p = s + row*4096;
  float4 v[4]; float m = -1e30f;
  #pragma unroll
  for(int i=0;i<4;++i){
    v[i] = *(const float4*)(p + (i*256+t)*4);
    m = fmaxf(m, fmaxf(fmaxf(v[i].x,v[i].y),fmaxf(v[i].z,v[i].w)));
  }
  m = blockMaxF(m, sm);
  float sum = 0.f;
  #pragma unroll
  for(int i=0;i<4;++i){
    v[i].x = __expf(v[i].x-m); v[i].y = __expf(v[i].y-m);
    v[i].z = __expf(v[i].z-m); v[i].w = __expf(v[i].w-m);
    sum += v[i].x+v[i].y+v[i].z+v[i].w;
  }
  float inv = 1.f/blockSumF(sum, sm);
  f16* o = a + row*4096;
  #pragma unroll
  for(int i=0;i<4;++i){
    f16x4 ov = {(f16)(v[i].x*inv),(f16)(v[i].y*inv),(f16)(v[i].z*inv),(f16)(v[i].w*inv)};
    *(f16x4*)(o + (i*256+t)*4) = ov;
  }
}

// ---------------- scale = 1/(max rowsum * max colsum) ------------------------
__global__ __launch_bounds__(256) void k_scale(const float* __restrict__ rs, const unsigned* __restrict__ csmax,
                                               float* __restrict__ scale){
  __shared__ float sm[4];
  int t = threadIdx.x;
  float m = fmaxf(fmaxf(rs[t],rs[t+256]), fmaxf(rs[t+512],rs[t+768]));
  m = blockMaxF(m, sm);
  if(t==0){ scale[0] = 1.f/(__uint_as_float(*csmax)*m); }
}

// ---------------- z0 = a2^T * scale ------------------------------------------
__global__ __launch_bounds__(256) void k_z0(const float* __restrict__ a2, const float* __restrict__ scale,
                                            float* __restrict__ z){
  __shared__ float tile[64][65];
  int b = blockIdx.z; int i0 = blockIdx.x*64, j0 = blockIdx.y*64;
  const float* A = a2 + (long)b*65536; float* Z = z + (long)b*65536;
  float sc = scale[0];
  int t = threadIdx.x; int c = t&63, r4 = t>>6;
  #pragma unroll
  for(int i=0;i<16;++i){ int r = i*4+r4; tile[r][c] = A[(j0+r)*256 + i0 + c]; }
  __syncthreads();
  #pragma unroll
  for(int i=0;i<16;++i){ int r = i*4+r4; Z[(i0+r)*256 + j0 + c] = tile[c][r]*sc; }
}

// ------- fp32 batched GEMM (256xK256 x [256][Ncols]): D = beta*(A@B)+alpha*E -
// LDS rows padded to 72 floats (288B = 18*16) so float4 LDS ops stay 16B-aligned.
__global__ __launch_bounds__(256) void gemm256(const float* __restrict__ A, const float* __restrict__ B,
    const float* __restrict__ E, float* __restrict__ D, int Ncols, float beta, float alpha){
  __shared__ float At[16][72];
  __shared__ float Bs[16][72];
  int b = blockIdx.z;
  A += (long)b*65536;
  B += (long)b*256*Ncols;
  D += (long)b*256*Ncols;
  if(E) E += (long)b*65536;
  int r0 = blockIdx.x*64, c0 = blockIdx.y*64;
  int t = threadIdx.x, tr = t>>4, tc = t&15;
  int arow = t>>2, ac4 = t&3;
  int bk = t>>4, bn4 = t&15;
  float acc[4][4] = {};
  for(int k0=0;k0<256;k0+=16){
    float4 va = *(const float4*)(A + (long)(r0+arow)*256 + k0 + ac4*4);
    At[ac4*4+0][arow]=va.x; At[ac4*4+1][arow]=va.y; At[ac4*4+2][arow]=va.z; At[ac4*4+3][arow]=va.w;
    *(float4*)&Bs[bk][bn4*4] = *(const float4*)(B + (long)(k0+bk)*Ncols + c0 + bn4*4);
    __syncthreads();
    #pragma unroll
    for(int kk=0;kk<16;++kk){
      float4 a4 = *(const float4*)&At[kk][tr*4];
      float4 b4 = *(const float4*)&Bs[kk][tc*4];
      float av[4] = {a4.x,a4.y,a4.z,a4.w};
      float bv[4] = {b4.x,b4.y,b4.z,b4.w};
      #pragma unroll
      for(int i=0;i<4;++i){
        #pragma unroll
        for(int j=0;j<4;++j) acc[i][j] += av[i]*bv[j];
      }
    }
    __syncthreads();
  }
  #pragma unroll
  for(int i=0;i<4;++i){
    int row = r0 + tr*4 + i;
    #pragma unroll
    for(int j=0;j<4;++j){
      int col = c0 + tc*4 + j;
      float v = beta*acc[i][j];
      if(E) v += alpha*E[row*256+col];
      D[(long)row*Ncols + col] = v;
    }
  }
}

// ---------------- z fp32 -> f16 ----------------------------------------------
__global__ __launch_bounds__(256) void k_zb(const float* __restrict__ z, f16* __restrict__ zb){
  int i = blockIdx.x*256 + threadIdx.x;
  zb[i] = (f16)z[i];
}

// ---------------- a3 f16 [b][256][4096] -> a3T f16 [b][4096][256] ------------
__global__ __launch_bounds__(256) void k_trA3(const f16* __restrict__ a3, f16* __restrict__ a3T){
  __shared__ f16 tile[64][74];
  int b = blockIdx.z; int n0 = blockIdx.x*64, m0 = blockIdx.y*64;
  const f16* A = a3 + (long)b*1048576; f16* T = a3T + (long)b*1048576;
  int t = threadIdx.x; int c = t&63, r4 = t>>6;
  #pragma unroll
  for(int i=0;i<16;++i){ int r = i*4+r4; tile[r][c] = A[(long)(m0+r)*4096 + n0 + c]; }
  __syncthreads();
  #pragma unroll
  for(int i=0;i<16;++i){ int nr = i*4+r4; T[(long)(n0+nr)*256 + m0 + c] = tile[c][nr]; }
}

// ------- final: outh = a1@za3v; + depthwise conv(v); @w_out + b_out; + x -----
__global__ __launch_bounds__(256) void k_final(
    const f16* __restrict__ a1, const float* __restrict__ za3v, const float* __restrict__ vf,
    const float* __restrict__ x, const float* __restrict__ wout, const float* __restrict__ bout,
    const float* __restrict__ wconv, float* __restrict__ out0)
{
  __shared__ f16 za[64*258];     // za3v^T, padded: [d][m]
  __shared__ f16 a1s[16*256];
  __shared__ float hs[16*64];
  __shared__ float wc[33];
  int t = threadIdx.x;
  int blk = blockIdx.x; int b = blk>>8; int ng = blk&255;
  long rowbase = (long)b*4096 + ng*16;
  const float* zg = za3v + (long)b*16384;
  for(int i=0;i<64;++i){ int idx = i*256+t; za[(idx&63)*258 + (idx>>6)] = (f16)zg[idx]; }
  const f16* ag = a1 + rowbase*256;
  #pragma unroll
  for(int i=0;i<16;++i){ int idx = i*256+t; a1s[idx] = ag[idx]; }
  if(t<33) wc[t] = wconv[t];
  __syncthreads();
  int d = t&63, q = t>>6;
  float acc[4] = {0.f,0.f,0.f,0.f};
  for(int mp=0;mp<128;++mp){
    f16x2 z2 = *(const f16x2*)&za[d*258 + mp*2];
    float z0 = (float)z2.x, z1 = (float)z2.y;
    #pragma unroll
    for(int j=0;j<4;++j){
      f16x2 a2v = *(const f16x2*)&a1s[(q+j*4)*256 + mp*2];
      acc[j] += (float)a2v.x*z0 + (float)a2v.y*z1;
    }
  }
  #pragma unroll
  for(int j=0;j<4;++j){
    int rloc = q + j*4;
    int n = ng*16 + rloc;
    float res = 0.f;
    for(int tau=0;tau<33;++tau){
      int nn = n + tau - 16;
      if(nn>=0 && nn<4096) res += wc[tau]*vf[((long)(b*4096+nn))*64 + d];
    }
    hs[rloc*64 + d] = acc[j] + res;
  }
  __syncthreads();
  int c0 = t, c1 = t+256;
  float o0[16], o1[16];
  float bb0 = bout[c0], bb1 = bout[c1];
  #pragma unroll
  for(int r=0;r<16;++r){ o0[r]=bb0; o1[r]=bb1; }
  for(int dd=0;dd<64;++dd){
    float w0 = wout[dd*512 + c0];
    float w1 = wout[dd*512 + c1];
    #pragma unroll
    for(int r=0;r<16;++r){
      float h = hs[r*64+dd];
      o0[r] += h*w0; o1[r] += h*w1;
    }
  }
  #pragma unroll
  for(int r=0;r<16;++r){
    long orow = (rowbase + r)*512;
    out0[orow + c0] = x[orow+c0] + o0[r];
    out0[orow + c1] = x[orow+c1] + o1[r];
  }
}

extern "C" void kernel_launch(void* const* d_in, const int* in_sizes, int n_in,
                              void* d_out, int out_size, void* d_ws, size_t ws_size,
                              hipStream_t stream) {
  (void)in_sizes; (void)n_in; (void)out_size; (void)ws_size;
  const float* x     = (const float*)d_in[0];
  const float* gamma = (const float*)d_in[1];
  const float* beta  = (const float*)d_in[2];
  const float* wqkv  = (const float*)d_in[3];
  const float* wout  = (const float*)d_in[4];
  const float* bout  = (const float*)d_in[5];
  const float* wconv = (const float*)d_in[6];

  char* ws = (char*)d_ws;
  f16*   xn   = (f16*)(ws + 0);
  float* s3   = (float*)(ws + 0);          // reuse after qkv gemm
  float* s1   = (float*)(ws + 16777216);
  f16*   a3T  = (f16*)(ws + 16777216);     // reuse after softmax1
  f16*   U    = (f16*)(ws + 25165824);
  float* qkv  = (float*)(ws + 33554432);
  f16*   a3   = (f16*)(ws + 33554432);     // reuse after split
  f16*   a1   = (f16*)(ws + 46137344);
  f16*   qf   = (f16*)(ws + 54525952);
  f16*   kf   = (f16*)(ws + 56623104);
  float* vf   = (float*)(ws + 58720256);
  f16*   vT   = (f16*)(ws + 62914560);
  f16*   wqkT = (f16*)(ws + 67108864);
  f16*   ql   = (f16*)(ws + 67371008);
  f16*   kl   = (f16*)(ws + 67502080);
  float* s2   = (float*)(ws + 67633152);
  float* a2   = (float*)(ws + 68681728);
  float* zA   = (float*)(ws + 69730304);
  float* zB   = (float*)(ws + 70778880);
  float* xz   = (float*)(ws + 71827456);
  float* t1   = (float*)(ws + 72876032);
  float* t2   = (float*)(ws + 73924608);
  f16*   zb   = (f16*)(ws + 74973184);
  float* a3v  = (float*)(ws + 75497472);
  float* za3v = (float*)(ws + 75759616);
  float* rs   = (float*)(ws + 76021760);
  unsigned* csmax = (unsigned*)(ws + 76021760 + 4096);
  float* scale    = (float*)(ws + 76021760 + 4160);

  float* out0 = (float*)d_out;
  float* attn = out0 + 8388608;

  hipMemsetAsync(ws + 76021760, 0, 8192, stream);

  k_ln<<<16384,256,0,stream>>>(x, gamma, beta, xn);
  k_trw<<<512,256,0,stream>>>(wqkv, wqkT);
  gemm_bt<float><<<dim3(128,2,1),256,0,stream>>>(xn, wqkT, qkv, 16384,192,512, 0L,0L,0L);
  k_split<<<4096,256,0,stream>>>(qkv, qf, kf, vf);
  k_vT<<<dim3(64,4),256,0,stream>>>(vf, vT);
  k_land<<<256,256,0,stream>>>(qf, kf, ql, kl);
  // sims
  gemm_bt<float><<<dim3(32,2,4),256,0,stream>>>(qf, kl, s1, 4096,256,64, 262144L,16384L,1048576L);
  gemm_bt<float><<<dim3(2,2,4),256,0,stream>>>(ql, kl, s2, 256,256,64, 16384L,16384L,65536L);
  gemm_bt<float><<<dim3(2,32,4),256,0,stream>>>(ql, kf, s3, 256,4096,64, 16384L,262144L,1048576L);
  k_softmax1<<<4096,256,0,stream>>>(s1, a1);
  k_softmax2<<<1024,256,0,stream>>>(s2, a2, rs, csmax);
  k_softmax3<<<1024,256,0,stream>>>(s3, a3);
  k_scale<<<1,256,0,stream>>>(rs, csmax, scale);
  k_z0<<<dim3(4,4,4),256,0,stream>>>(a2, scale, zA);
  // Newton-Schulz pinv, 6 iterations, fp32
  float* cur = zA; float* nxt = zB;
  for(int it=0; it<6; ++it){
    gemm256<<<dim3(4,4,4),256,0,stream>>>(a2, cur, (const float*)nullptr, xz, 256, 1.f, 0.f);
    gemm256<<<dim3(4,4,4),256,0,stream>>>(xz, xz, xz, t1, 256, -1.f, 7.f);
    gemm256<<<dim3(4,4,4),256,0,stream>>>(xz, t1, xz, t2, 256, -1.f, 15.f);
    gemm256<<<dim3(4,4,4),256,0,stream>>>(cur, t2, cur, nxt, 256, -0.25f, 3.25f);
    float* tmp = cur; cur = nxt; nxt = tmp;
  }
  // cur == zA after 6 iterations
  k_zb<<<1024,256,0,stream>>>(cur, zb);
  k_trA3<<<dim3(64,4,4),256,0,stream>>>(a3, a3T);
  gemm_bt<float><<<dim3(2,1,4),256,0,stream>>>(a3, vT, a3v, 256,64,4096, 1048576L,524288L,16384L);
  gemm256<<<dim3(4,1,4),256,0,stream>>>(cur, a3v, (const float*)nullptr, za3v, 64, 1.f, 0.f);
  gemm_bt<f16><<<dim3(32,2,4),256,0,stream>>>(a3T, zb, U, 4096,256,256, 1048576L,65536L,1048576L);
  gemm_bt<float><<<dim3(32,32,4),256,0,stream>>>(a1, U, attn, 4096,4096,256, 1048576L,1048576L,16777216L);
  k_final<<<1024,256,0,stream>>>(a1, za3v, vf, x, wout, bout, wconv, out0);
}